// Round 10
// baseline (4019.493 us; speedup 1.0000x reference)
//
#include <hip/hip_runtime.h>
#include <math.h>

#define N_NODES 4000
#define CC 191
#define CP 192
#define NT 3
#define NB 5
#define NS 10
#define EE 12000
#define GG 32
#define THREE_C 573
#define NC (N_NODES * CP)
#define NPAD 576

typedef __attribute__((ext_vector_type(8))) short short8;
typedef __attribute__((ext_vector_type(4))) float f32x4;

__device__ __forceinline__ unsigned short f2bf(float f) {
    unsigned u = __float_as_uint(f);
    unsigned r = (u + 0x7fffu + ((u >> 16) & 1u)) >> 16;
    return (unsigned short)r;
}
__device__ __forceinline__ float bf2f(unsigned short s) {
    return __uint_as_float(((unsigned)s) << 16);
}
// async global->LDS DMA, 16B per lane; lds dest = wave-uniform base + lane*16
__device__ __forceinline__ void dma16(const void* g, void* l) {
    __builtin_amdgcn_global_load_lds(
        (const __attribute__((address_space(1))) unsigned int*)g,
        (__attribute__((address_space(3))) unsigned int*)l, 16, 0, 0);
}

// ---------------------------------------------------------------- build h
__global__ void k_build_h(const float* __restrict__ xs, const int* __restrict__ xtype,
                          const int* __restrict__ xtok, float* __restrict__ h) {
    int idx = blockIdx.x * 256 + threadIdx.x;
    if (idx >= NC) return;
    int i = idx / CP, c = idx % CP;
    float v = 0.f;
    if (c < 60) {
        v = (xtype[i] == c) ? 1.f : 0.f;
    } else if (c < 189) {
        int tk = xtok[i];
        tk = tk < 0 ? 0 : (tk > 128 ? 128 : tk);
        v = (tk == c - 60) ? 1.f : 0.f;
    } else if (c < CC) {
        v = xs[i * 2 + (c - 189)];
    }
    h[idx] = v;
}

// ---- split gate-matrices (wih or whh, raw [nbt][573][191]) -> hi/lo bf16
// permuted rows: p -> B0=p/96, v=(p%96)>>4, u=p&15 : gate=v%3, j=B0*32+(v/3)*16+u
__global__ void k_split_gates(const float* __restrict__ src, unsigned short* __restrict__ H,
                              unsigned short* __restrict__ L, int nbt) {
    long tot = (long)nbt * NPAD * CP;
    long idx = (long)blockIdx.x * 256 + threadIdx.x;
    if (idx >= tot) return;
    int q = (int)(idx % CP);
    int p = (int)((idx / CP) % NPAD);
    int bt = (int)(idx / ((long)NPAD * CP));
    int B0 = p / 96, pr = p % 96;
    int v = pr >> 4, u = pr & 15;
    int g = v % 3;
    int j = B0 * 32 + (v / 3) * 16 + u;
    float val = 0.f;
    if (j < CC && q < CC) val = src[((long)bt * THREE_C + g * CC + j) * CC + q];
    unsigned short hi = f2bf(val);
    H[idx] = hi;
    L[idx] = f2bf(val - bf2f(hi));
}

// ---- split conv (raw [150][191][191]) -> hi/lo bf16 [150][192][192]
__global__ void k_split_conv(const float* __restrict__ src, unsigned short* __restrict__ H,
                             unsigned short* __restrict__ L) {
    long tot = 150L * 192 * 192;
    long idx = (long)blockIdx.x * 256 + threadIdx.x;
    if (idx >= tot) return;
    int q = (int)(idx % 192);
    int k = (int)((idx / 192) % 192);
    int ts = (int)(idx / (192 * 192));
    float val = 0.f;
    if (k < CC && q < CC) val = src[((long)ts * CC + k) * CC + q];
    unsigned short hi = f2bf(val);
    H[idx] = hi;
    L[idx] = f2bf(val - bf2f(hi));
}

// --------------------------------------------------------------- CSR build
__global__ void k_edge_count(const int* __restrict__ ei, const int* __restrict__ et,
                             int* __restrict__ cnt) {
    int e = blockIdx.x * 256 + threadIdx.x;
    if (e >= EE) return;
    atomicAdd(&cnt[et[e] * N_NODES + ei[EE + e]], 1);
}

__global__ void k_scan(const int* __restrict__ cnt, int* __restrict__ off, int* __restrict__ fill) {
    const int TOT = NT * N_NODES;
    const int CH = (TOT + 255) / 256;
    __shared__ int ls[256];
    int tid = threadIdx.x;
    int base = tid * CH;
    int s = 0;
    for (int u = 0; u < CH; u++) {
        int idx = base + u;
        if (idx < TOT) s += cnt[idx];
    }
    ls[tid] = s;
    __syncthreads();
    for (int d = 1; d < 256; d <<= 1) {
        int v = 0;
        if (tid >= d) v = ls[tid - d];
        __syncthreads();
        if (tid >= d) ls[tid] += v;
        __syncthreads();
    }
    int run = (tid > 0) ? ls[tid - 1] : 0;
    for (int u = 0; u < CH; u++) {
        int idx = base + u;
        if (idx < TOT) {
            off[idx] = run;
            fill[idx] = run;
            run += cnt[idx];
        }
    }
    if (tid == 255) off[TOT] = run;
}

__global__ void k_edge_fill(const int* __restrict__ ei, const int* __restrict__ et,
                            int* __restrict__ fill, int* __restrict__ csrc) {
    int e = blockIdx.x * 256 + threadIdx.x;
    if (e >= EE) return;
    int pos = atomicAdd(&fill[et[e] * N_NODES + ei[EE + e]], 1);
    csrc[pos] = ei[e];
}

// =========== MFMA F-precompute: F[ts][p][k] = sum_q wihP[bt][p][q]*convP[ts][k][q]
__global__ __launch_bounds__(256, 4) void k_fmat_mfma(
        const unsigned short* __restrict__ AH, const unsigned short* __restrict__ AL,
        const unsigned short* __restrict__ BH, const unsigned short* __restrict__ BL,
        unsigned short* __restrict__ FH, unsigned short* __restrict__ FL, int b) {
    const int ts = blockIdx.z;
    const int t = ts / NS;
    const int M0 = blockIdx.x * 96;
    const int N0 = blockIdx.y * 96;
    __shared__ __align__(16) char smem[24576];

    const int tid = threadIdx.x;
    const int lane = tid & 63;
    const int wave = tid >> 6;
    const int wm = wave & 1;
    const int wn = wave >> 1;
    const int l15 = lane & 15;
    const int kb = lane >> 4;
    const int ldso = (tid & 192) << 4;

    const unsigned short* gA[2];
    gA[0] = AH + (size_t)(b * 3 + t) * NPAD * CP;
    gA[1] = AL + (size_t)(b * 3 + t) * NPAD * CP;
    const unsigned short* gB[2];
    gB[0] = BH + (size_t)(b * 30 + ts) * 192 * 192;
    gB[1] = BL + (size_t)(b * 30 + ts) * 192 * 192;

    f32x4 acc[3][3];
    #pragma unroll
    for (int mi = 0; mi < 3; mi++)
        #pragma unroll
        for (int nj = 0; nj < 3; nj++) acc[mi][nj] = (f32x4){0.f, 0.f, 0.f, 0.f};

    for (int k = 0; k < 6; k++) {
        const int ko = k * 32;
        __syncthreads();
        #pragma unroll
        for (int i = 0; i < 6; i++) {
            int c = i * 256 + tid;
            int a = c / 384;
            int rem = c - a * 384;
            int r = rem >> 2, qs = rem & 3;
            int q = qs ^ ((r >> 1) & 3);
            const unsigned short* g = (a < 2) ? gA[a] : gB[a - 2];
            int row = ((a < 2) ? M0 : N0) + r;
            dma16(g + (size_t)row * CP + ko + q * 8, smem + i * 4096 + ldso);
        }
        __syncthreads();

        short8 ah[3], al[3], bh[3], bl[3];
        #pragma unroll
        for (int mi = 0; mi < 3; mi++) {
            int r = wm * 48 + mi * 16 + l15;
            int sl = (r * 4 + (kb ^ ((r >> 1) & 3))) * 16;
            ah[mi] = *(const short8*)(smem + sl);
            al[mi] = *(const short8*)(smem + 6144 + sl);
        }
        #pragma unroll
        for (int nj = 0; nj < 3; nj++) {
            int r = wn * 48 + nj * 16 + l15;
            int sl = (r * 4 + (kb ^ ((r >> 1) & 3))) * 16;
            bh[nj] = *(const short8*)(smem + 12288 + sl);
            bl[nj] = *(const short8*)(smem + 18432 + sl);
        }
        #pragma unroll
        for (int mi = 0; mi < 3; mi++)
            #pragma unroll
            for (int nj = 0; nj < 3; nj++) {
                acc[mi][nj] = __builtin_amdgcn_mfma_f32_16x16x32_bf16(
                    ah[mi], bh[nj], acc[mi][nj], 0, 0, 0);
                acc[mi][nj] = __builtin_amdgcn_mfma_f32_16x16x32_bf16(
                    al[mi], bh[nj], acc[mi][nj], 0, 0, 0);
                acc[mi][nj] = __builtin_amdgcn_mfma_f32_16x16x32_bf16(
                    ah[mi], bl[nj], acc[mi][nj], 0, 0, 0);
            }
    }
    #pragma unroll
    for (int mi = 0; mi < 3; mi++)
        #pragma unroll
        for (int nj = 0; nj < 3; nj++)
            #pragma unroll
            for (int r = 0; r < 4; r++) {
                int p = M0 + wm * 48 + mi * 16 + kb * 4 + r;
                int kc = N0 + wn * 48 + nj * 16 + l15;
                float val = acc[mi][nj][r];
                unsigned short hi = f2bf(val);
                size_t o = ((size_t)ts * NPAD + p) * CP + kc;
                FH[o] = hi;
                FL[o] = f2bf(val - bf2f(hi));
            }
}

// ------------------- h fp32 -> X0 hi/lo bf16 for the 3 type-chains
__global__ void k_split3(const float* __restrict__ h, unsigned short* __restrict__ XH,
                         unsigned short* __restrict__ XL) {
    int idx = blockIdx.x * 256 + threadIdx.x;
    if (idx >= NC) return;
    float f = h[idx];
    unsigned short hi = f2bf(f);
    unsigned short lo = f2bf(f - bf2f(hi));
    #pragma unroll
    for (int t = 0; t < NT; t++) {
        XH[(long)t * NC + idx] = hi;
        XL[(long)t * NC + idx] = lo;
    }
}

// ------------------- Agg hi/lo from X hi/lo via CSR gather
__global__ void k_agg(const unsigned short* __restrict__ XH, const unsigned short* __restrict__ XL,
                      unsigned short* __restrict__ AH, unsigned short* __restrict__ AL,
                      const int* __restrict__ off, const int* __restrict__ csrc) {
    int node = blockIdx.x;
    int t = blockIdx.y;
    int k = threadIdx.x;   // 192
    const unsigned short* Xh = XH + (long)t * NC;
    const unsigned short* Xl = XL + (long)t * NC;
    int e0 = off[t * N_NODES + node];
    int e1 = off[t * N_NODES + node + 1];
    float s = 0.f;
    for (int e = e0; e < e1; e++) {
        long base = (long)csrc[e] * CP + k;
        s += bf2f(Xh[base]) + bf2f(Xl[base]);
    }
    unsigned short hi = f2bf(s);
    long o = ((long)t * N_NODES + node) * CP + k;
    AH[o] = hi;
    AL[o] = f2bf(s - bf2f(hi));
}

// =================== hot kernel: dual MFMA GEMM + register GRU epilogue
// tile 128M x 96N, K=192 in 6 stages of 32; compensated bf16 (hh + lh + hl).
// A (X/Agg hi+lo) + B-hi (FH/WH) DMA-staged in LDS (44 KB -> 3 blocks/CU, grid
// fits in ONE cohort); B-lo (FL/WL) read as direct 16B global fragments (L2-hot,
// 32x reuse across M-blocks; issued before the barrier whose vmcnt(0) lands them).
__global__ __launch_bounds__(256, 3) void k_step(
        const unsigned short* __restrict__ XcH, const unsigned short* __restrict__ XcL,
        const unsigned short* __restrict__ AgH, const unsigned short* __restrict__ AgL,
        const unsigned short* __restrict__ FH, const unsigned short* __restrict__ FL,
        const unsigned short* __restrict__ WH, const unsigned short* __restrict__ WL,
        const float* __restrict__ bih, const float* __restrict__ bhh,
        unsigned short* __restrict__ XnH, unsigned short* __restrict__ XnL,
        int b, int s) {
    const int t = blockIdx.z;
    const int ts = t * NS + s;
    const int M0 = blockIdx.x * 128;
    const int N0 = blockIdx.y * 96;

    // byte layout: A arrays (XH,GH,XL,GL) @ a*8192, 128 rows x 4 slots x 16B
    //              B-hi arrays (FH,WH) @ 32768 + a*6144, 96 rows x 4 slots x 16B
    __shared__ __align__(16) char smem[45056];

    const int tid = threadIdx.x;
    const int lane = tid & 63;
    const int wave = tid >> 6;
    const int wm = wave & 1;
    const int wn = wave >> 1;
    const int l15 = lane & 15;
    const int kb = lane >> 4;

    const unsigned short* gA[4];
    gA[0] = XcH + (size_t)t * NC;
    gA[1] = AgH + (size_t)t * NC;
    gA[2] = XcL + (size_t)t * NC;
    gA[3] = AgL + (size_t)t * NC;
    const unsigned short* gBh[2];
    gBh[0] = FH + (size_t)ts * NPAD * CP;
    gBh[1] = WH + (size_t)(b * 3 + t) * NPAD * CP;
    const unsigned short* Flo = FL + (size_t)ts * NPAD * CP;
    const unsigned short* Wlo = WL + (size_t)(b * 3 + t) * NPAD * CP;

    // direct-fragment offsets for the B-lo arrays (16B contiguous per lane)
    size_t boff[3];
    #pragma unroll
    for (int nj = 0; nj < 3; nj++)
        boff[nj] = (size_t)(N0 + wn * 48 + nj * 16 + l15) * CP + kb * 8;

    f32x4 accGI[4][3], accGH[4][3];
    #pragma unroll
    for (int mi = 0; mi < 4; mi++)
        #pragma unroll
        for (int nj = 0; nj < 3; nj++) {
            accGI[mi][nj] = (f32x4){0.f, 0.f, 0.f, 0.f};
            accGH[mi][nj] = (f32x4){0.f, 0.f, 0.f, 0.f};
        }

    const int ldso = (tid & 192) << 4;
    const int qsA = tid & 3;
    const int rA_lo = tid >> 2;

    for (int k = 0; k < 6; k++) {
        const int ko = k * 32;
        __syncthreads();
        // ---- A: 4 arrays x 128 rows x 32 half; iter i covers 256 slots
        #pragma unroll
        for (int i = 0; i < 8; i++) {
            int a = i >> 1;
            int r = (i & 1) * 64 + rA_lo;
            int q = qsA ^ ((r >> 1) & 3);
            int node = M0 + r; node = node < N_NODES ? node : N_NODES - 1;
            dma16(gA[a] + (size_t)node * CP + ko + q * 8, smem + i * 4096 + ldso);
        }
        // ---- B-hi: 2 arrays x 96 rows x 32 half (768 slots)
        #pragma unroll
        for (int i = 0; i < 3; i++) {
            int c = i * 256 + tid;
            int a = c / 384;
            int rem = c - a * 384;
            int r = rem >> 2, qs = rem & 3;
            int q = qs ^ ((r >> 1) & 3);
            dma16(gBh[a] + (size_t)(N0 + r) * CP + ko + q * 8, smem + 32768 + i * 4096 + ldso);
        }
        // ---- B-lo direct global fragment loads (land at the barrier's vmcnt(0))
        short8 fl[3], wl[3];
        #pragma unroll
        for (int nj = 0; nj < 3; nj++) {
            fl[nj] = *(const short8*)(Flo + boff[nj] + ko);
            wl[nj] = *(const short8*)(Wlo + boff[nj] + ko);
        }
        __syncthreads();

        short8 xh[4], gh[4], xl[4], gl[4];
        #pragma unroll
        for (int mi = 0; mi < 4; mi++) {
            int r = wm * 64 + mi * 16 + l15;
            int sl = (r * 4 + (kb ^ ((r >> 1) & 3))) * 16;
            xh[mi] = *(const short8*)(smem + sl);
            gh[mi] = *(const short8*)(smem + 8192 + sl);
            xl[mi] = *(const short8*)(smem + 16384 + sl);
            gl[mi] = *(const short8*)(smem + 24576 + sl);
        }
        short8 fh[3], wh[3];
        #pragma unroll
        for (int nj = 0; nj < 3; nj++) {
            int r = wn * 48 + nj * 16 + l15;
            int sl = (r * 4 + (kb ^ ((r >> 1) & 3))) * 16;
            fh[nj] = *(const short8*)(smem + 32768 + sl);
            wh[nj] = *(const short8*)(smem + 38912 + sl);
        }
        #pragma unroll
        for (int mi = 0; mi < 4; mi++)
            #pragma unroll
            for (int nj = 0; nj < 3; nj++) {
                accGI[mi][nj] = __builtin_amdgcn_mfma_f32_16x16x32_bf16(
                    gh[mi], fh[nj], accGI[mi][nj], 0, 0, 0);
                accGI[mi][nj] = __builtin_amdgcn_mfma_f32_16x16x32_bf16(
                    gl[mi], fh[nj], accGI[mi][nj], 0, 0, 0);
                accGI[mi][nj] = __builtin_amdgcn_mfma_f32_16x16x32_bf16(
                    gh[mi], fl[nj], accGI[mi][nj], 0, 0, 0);
                accGH[mi][nj] = __builtin_amdgcn_mfma_f32_16x16x32_bf16(
                    xh[mi], wh[nj], accGH[mi][nj], 0, 0, 0);
                accGH[mi][nj] = __builtin_amdgcn_mfma_f32_16x16x32_bf16(
                    xl[mi], wh[nj], accGH[mi][nj], 0, 0, 0);
                accGH[mi][nj] = __builtin_amdgcn_mfma_f32_16x16x32_bf16(
                    xh[mi], wl[nj], accGH[mi][nj], 0, 0, 0);
            }
    }

    // ---------------- register-only GRU epilogue
    const int J = blockIdx.y * 32 + wn * 16 + l15;
    const bool jv = (J < CC);
    const int Je = jv ? J : 0;
    const int bo = (b * 3 + t) * THREE_C;
    const float bir = bih[bo + Je], biz = bih[bo + CC + Je], bic = bih[bo + 2 * CC + Je];
    const float bhr = bhh[bo + Je], bhz = bhh[bo + CC + Je], bhc = bhh[bo + 2 * CC + Je];
    #pragma unroll
    for (int mi = 0; mi < 4; mi++) {
        #pragma unroll
        for (int r = 0; r < 4; r++) {
            int node = M0 + wm * 64 + mi * 16 + kb * 4 + r;
            if (node < N_NODES && jv) {
                size_t xi = (size_t)(t * N_NODES + node) * CP + J;
                float xold = bf2f(XcH[xi]) + bf2f(XcL[xi]);
                float rr = 1.f / (1.f + expf(-(accGI[mi][0][r] + bir + accGH[mi][0][r] + bhr)));
                float zz = 1.f / (1.f + expf(-(accGI[mi][1][r] + biz + accGH[mi][1][r] + bhz)));
                float cg = tanhf(accGI[mi][2][r] + bic + rr * (accGH[mi][2][r] + bhc));
                float outv = (1.f - zz) * cg + zz * xold;
                unsigned short oh = f2bf(outv);
                XnH[xi] = oh;
                XnL[xi] = f2bf(outv - bf2f(oh));
            }
        }
    }
}

// --------------------------------------------------------- LayerNorm + ReLU
__global__ void k_ln(float* __restrict__ h, const unsigned short* __restrict__ XH,
                     const unsigned short* __restrict__ XL,
                     const float* __restrict__ lnw, const float* __restrict__ lnb, int b) {
    int i = blockIdx.x;
    int c = threadIdx.x;
    long base = (long)i * CP + c;
    float v = 0.f;
    if (c < CC) {
        v = h[base];
        #pragma unroll
        for (int t = 0; t < NT; t++)
            v += bf2f(XH[(long)t * NC + base]) + bf2f(XL[(long)t * NC + base]);
    }
    float sv = v;
    for (int o = 32; o > 0; o >>= 1) sv += __shfl_down(sv, o);
    __shared__ float ls[3];
    __shared__ float bc[2];
    if ((threadIdx.x & 63) == 0) ls[threadIdx.x >> 6] = sv;
    __syncthreads();
    if (threadIdx.x == 0) bc[0] = (ls[0] + ls[1] + ls[2]) / (float)CC;
    __syncthreads();
    float mu = bc[0];
    float d = (c < CC) ? (v - mu) : 0.f;
    float s2 = d * d;
    for (int o = 32; o > 0; o >>= 1) s2 += __shfl_down(s2, o);
    __syncthreads();
    if ((threadIdx.x & 63) == 0) ls[threadIdx.x >> 6] = s2;
    __syncthreads();
    if (threadIdx.x == 0) bc[1] = (ls[0] + ls[1] + ls[2]) / (float)CC;
    __syncthreads();
    float var = bc[1];
    float y = 0.f;
    if (c < CC) {
        y = d * rsqrtf(var + 1e-5f) * lnw[b * CC + c] + lnb[b * CC + c];
        y = y > 0.f ? y : 0.f;
    }
    h[base] = y;
}

// --------------------------------------------------------------- pooling
__global__ void k_pool(const float* __restrict__ h, const int* __restrict__ batch,
                       float* __restrict__ hg, float* __restrict__ gcnt) {
    int idx = blockIdx.x * 256 + threadIdx.x;
    if (idx >= NC) return;
    int i = idx / CP, c = idx % CP;
    int g = batch[i];
    if (c < CC) atomicAdd(&hg[g * CP + c], h[idx]);
    if (c == 0) atomicAdd(&gcnt[g], 1.f);
}

__global__ void k_head1(const float* __restrict__ hg, const float* __restrict__ gcnt,
                        const float* __restrict__ w1, const float* __restrict__ b1,
                        float* __restrict__ z1) {
    int g = blockIdx.x;
    int jcol = threadIdx.x;
    if (jcol >= CC) return;
    float inv = 1.f / fmaxf(gcnt[g], 1.f);
    float acc = 0.f;
    for (int k = 0; k < CC; k++) acc += hg[g * CP + k] * inv * w1[k * CC + jcol];
    acc += b1[jcol];
    z1[g * CP + jcol] = fmaxf(acc, 0.f);
}

__global__ void k_head2(const float* __restrict__ z1, const float* __restrict__ w2,
                        const float* __restrict__ b2, float* __restrict__ out) {
    int idx = threadIdx.x;
    if (idx >= GG * 2) return;
    int g = idx / 2, o = idx % 2;
    float acc = 0.f;
    for (int k = 0; k < CC; k++) acc += z1[g * CP + k] * w2[k * 2 + o];
    out[g * 2 + o] = acc + b2[o];
}

// ================================================================ launch
extern "C" void kernel_launch(void* const* d_in, const int* in_sizes, int n_in,
                              void* d_out, int out_size, void* d_ws, size_t ws_size,
                              hipStream_t stream) {
    const float* xs   = (const float*)d_in[0];
    const float* conv = (const float*)d_in[1];
    const float* wih  = (const float*)d_in[2];
    const float* whh  = (const float*)d_in[3];
    const float* bih  = (const float*)d_in[4];
    const float* bhh  = (const float*)d_in[5];
    const float* lnw  = (const float*)d_in[6];
    const float* lnb  = (const float*)d_in[7];
    const float* hw1  = (const float*)d_in[8];
    const float* hb1  = (const float*)d_in[9];
    const float* hw2  = (const float*)d_in[10];
    const float* hb2  = (const float*)d_in[11];
    const int* xtype  = (const int*)d_in[12];
    const int* xtok   = (const int*)d_in[13];
    const int* ei     = (const int*)d_in[14];
    const int* et     = (const int*)d_in[15];
    const int* batch  = (const int*)d_in[16];
    float* out = (float*)d_out;

    char* ws = (char*)d_ws;
    size_t o = 0;
    auto alloc = [&](size_t nbytes) {
        size_t r = o;
        o = (o + nbytes + 255) & ~(size_t)255;
        return r;
    };
    float* h      = (float*)(ws + alloc((size_t)NC * 4));
    unsigned short* FH    = (unsigned short*)(ws + alloc((size_t)30 * NPAD * CP * 2));
    unsigned short* FL    = (unsigned short*)(ws + alloc((size_t)30 * NPAD * CP * 2));
    unsigned short* WHH   = (unsigned short*)(ws + alloc((size_t)15 * NPAD * CP * 2));
    unsigned short* WHL   = (unsigned short*)(ws + alloc((size_t)15 * NPAD * CP * 2));
    unsigned short* wihH  = (unsigned short*)(ws + alloc((size_t)15 * NPAD * CP * 2));
    unsigned short* wihL  = (unsigned short*)(ws + alloc((size_t)15 * NPAD * CP * 2));
    unsigned short* convH = (unsigned short*)(ws + alloc((size_t)150 * 192 * 192 * 2));
    unsigned short* convL = (unsigned short*)(ws + alloc((size_t)150 * 192 * 192 * 2));
    unsigned short* XAh = (unsigned short*)(ws + alloc((size_t)NT * NC * 2));
    unsigned short* XAl = (unsigned short*)(ws + alloc((size_t)NT * NC * 2));
    unsigned short* XBh = (unsigned short*)(ws + alloc((size_t)NT * NC * 2));
    unsigned short* XBl = (unsigned short*)(ws + alloc((size_t)NT * NC * 2));
    unsigned short* AggH = (unsigned short*)(ws + alloc((size_t)NT * NC * 2));
    unsigned short* AggL = (unsigned short*)(ws + alloc((size_t)NT * NC * 2));
    float* hg     = (float*)(ws + alloc((size_t)GG * CP * 4));
    float* gcnt   = (float*)(ws + alloc((size_t)GG * 4));
    float* z1buf  = (float*)(ws + alloc((size_t)GG * CP * 4));
    int* cnt      = (int*)(ws + alloc((size_t)NT * N_NODES * 4));
    int* offb     = (int*)(ws + alloc((size_t)(NT * N_NODES + 1) * 4));
    int* fillb    = (int*)(ws + alloc((size_t)NT * N_NODES * 4));
    int* csrc     = (int*)(ws + alloc((size_t)EE * 4));
    (void)ws_size; (void)n_in; (void)in_sizes; (void)out_size;

    hipMemsetAsync(cnt, 0, (size_t)NT * N_NODES * 4, stream);
    hipMemsetAsync(hg, 0, (size_t)GG * CP * 4, stream);
    hipMemsetAsync(gcnt, 0, (size_t)GG * 4, stream);

    k_build_h<<<(NC + 255) / 256, 256, 0, stream>>>(xs, xtype, xtok, h);
    k_split_gates<<<(int)((15L * NPAD * CP + 255) / 256), 256, 0, stream>>>(wih, wihH, wihL, 15);
    k_split_gates<<<(int)((15L * NPAD * CP + 255) / 256), 256, 0, stream>>>(whh, WHH, WHL, 15);
    k_split_conv<<<(int)((150L * 192 * 192 + 255) / 256), 256, 0, stream>>>(conv, convH, convL);
    k_edge_count<<<(EE + 255) / 256, 256, 0, stream>>>(ei, et, cnt);
    k_scan<<<1, 256, 0, stream>>>(cnt, offb, fillb);
    k_edge_fill<<<(EE + 255) / 256, 256, 0, stream>>>(ei, et, fillb, csrc);

    for (int b = 0; b < NB; b++) {
        k_fmat_mfma<<<dim3(6, 2, 30), 256, 0, stream>>>(wihH, wihL, convH, convL, FH, FL, b);
        k_split3<<<(NC + 255) / 256, 256, 0, stream>>>(h, XAh, XAl);
        unsigned short *curH = XAh, *curL = XAl, *nxtH = XBh, *nxtL = XBl;
        for (int s = 0; s < NS; s++) {
            k_agg<<<dim3(N_NODES, NT), CP, 0, stream>>>(curH, curL, AggH, AggL, offb, csrc);
            dim3 sg(32, 6, NT);
            k_step<<<sg, 256, 0, stream>>>(curH, curL, AggH, AggL, FH, FL, WHH, WHL,
                                           bih, bhh, nxtH, nxtL, b, s);
            unsigned short* t1 = curH; curH = nxtH; nxtH = t1;
            unsigned short* t2 = curL; curL = nxtL; nxtL = t2;
        }
        k_ln<<<N_NODES, CP, 0, stream>>>(h, XAh, XAl, lnw, lnb, b);
    }

    k_pool<<<(NC + 255) / 256, 256, 0, stream>>>(h, batch, hg, gcnt);
    k_head1<<<GG, CP, 0, stream>>>(hg, gcnt, hw1, hb1, z1buf);
    k_head2<<<1, 64, 0, stream>>>(z1buf, hw2, hb2, out);
}

// Round 11
// 3301.487 us; speedup vs baseline: 1.2175x; 1.2175x over previous
//
#include <hip/hip_runtime.h>
#include <math.h>

#define N_NODES 4000
#define CC 191
#define CP 192
#define NT 3
#define NB 5
#define NS 10
#define EE 12000
#define GG 32
#define THREE_C 573
#define NC (N_NODES * CP)
#define NPAD 576

typedef __attribute__((ext_vector_type(8))) short short8;
typedef __attribute__((ext_vector_type(4))) float f32x4;

__device__ __forceinline__ unsigned short f2bf(float f) {
    unsigned u = __float_as_uint(f);
    unsigned r = (u + 0x7fffu + ((u >> 16) & 1u)) >> 16;
    return (unsigned short)r;
}
__device__ __forceinline__ float bf2f(unsigned short s) {
    return __uint_as_float(((unsigned)s) << 16);
}
// async global->LDS DMA, 16B per lane; lds dest = wave-uniform base + lane*16
__device__ __forceinline__ void dma16(const void* g, void* l) {
    __builtin_amdgcn_global_load_lds(
        (const __attribute__((address_space(1))) unsigned int*)g,
        (__attribute__((address_space(3))) unsigned int*)l, 16, 0, 0);
}

// ---------------------------------------------------------------- build h
__global__ void k_build_h(const float* __restrict__ xs, const int* __restrict__ xtype,
                          const int* __restrict__ xtok, float* __restrict__ h) {
    int idx = blockIdx.x * 256 + threadIdx.x;
    if (idx >= NC) return;
    int i = idx / CP, c = idx % CP;
    float v = 0.f;
    if (c < 60) {
        v = (xtype[i] == c) ? 1.f : 0.f;
    } else if (c < 189) {
        int tk = xtok[i];
        tk = tk < 0 ? 0 : (tk > 128 ? 128 : tk);
        v = (tk == c - 60) ? 1.f : 0.f;
    } else if (c < CC) {
        v = xs[i * 2 + (c - 189)];
    }
    h[idx] = v;
}

// ---- split gate-matrices (wih or whh, raw [nbt][573][191]) -> hi/lo bf16
// permuted rows: p -> B0=p/96, v=(p%96)>>4, u=p&15 : gate=v%3, j=B0*32+(v/3)*16+u
__global__ void k_split_gates(const float* __restrict__ src, unsigned short* __restrict__ H,
                              unsigned short* __restrict__ L, int nbt) {
    long tot = (long)nbt * NPAD * CP;
    long idx = (long)blockIdx.x * 256 + threadIdx.x;
    if (idx >= tot) return;
    int q = (int)(idx % CP);
    int p = (int)((idx / CP) % NPAD);
    int bt = (int)(idx / ((long)NPAD * CP));
    int B0 = p / 96, pr = p % 96;
    int v = pr >> 4, u = pr & 15;
    int g = v % 3;
    int j = B0 * 32 + (v / 3) * 16 + u;
    float val = 0.f;
    if (j < CC && q < CC) val = src[((long)bt * THREE_C + g * CC + j) * CC + q];
    unsigned short hi = f2bf(val);
    H[idx] = hi;
    L[idx] = f2bf(val - bf2f(hi));
}

// ---- split conv (raw [150][191][191]) -> hi/lo bf16 [150][192][192]
__global__ void k_split_conv(const float* __restrict__ src, unsigned short* __restrict__ H,
                             unsigned short* __restrict__ L) {
    long tot = 150L * 192 * 192;
    long idx = (long)blockIdx.x * 256 + threadIdx.x;
    if (idx >= tot) return;
    int q = (int)(idx % 192);
    int k = (int)((idx / 192) % 192);
    int ts = (int)(idx / (192 * 192));
    float val = 0.f;
    if (k < CC && q < CC) val = src[((long)ts * CC + k) * CC + q];
    unsigned short hi = f2bf(val);
    H[idx] = hi;
    L[idx] = f2bf(val - bf2f(hi));
}

// --------------------------------------------------------------- CSR build
__global__ void k_edge_count(const int* __restrict__ ei, const int* __restrict__ et,
                             int* __restrict__ cnt) {
    int e = blockIdx.x * 256 + threadIdx.x;
    if (e >= EE) return;
    atomicAdd(&cnt[et[e] * N_NODES + ei[EE + e]], 1);
}

__global__ void k_scan(const int* __restrict__ cnt, int* __restrict__ off, int* __restrict__ fill) {
    const int TOT = NT * N_NODES;
    const int CH = (TOT + 255) / 256;
    __shared__ int ls[256];
    int tid = threadIdx.x;
    int base = tid * CH;
    int s = 0;
    for (int u = 0; u < CH; u++) {
        int idx = base + u;
        if (idx < TOT) s += cnt[idx];
    }
    ls[tid] = s;
    __syncthreads();
    for (int d = 1; d < 256; d <<= 1) {
        int v = 0;
        if (tid >= d) v = ls[tid - d];
        __syncthreads();
        if (tid >= d) ls[tid] += v;
        __syncthreads();
    }
    int run = (tid > 0) ? ls[tid - 1] : 0;
    for (int u = 0; u < CH; u++) {
        int idx = base + u;
        if (idx < TOT) {
            off[idx] = run;
            fill[idx] = run;
            run += cnt[idx];
        }
    }
    if (tid == 255) off[TOT] = run;
}

__global__ void k_edge_fill(const int* __restrict__ ei, const int* __restrict__ et,
                            int* __restrict__ fill, int* __restrict__ csrc) {
    int e = blockIdx.x * 256 + threadIdx.x;
    if (e >= EE) return;
    int pos = atomicAdd(&fill[et[e] * N_NODES + ei[EE + e]], 1);
    csrc[pos] = ei[e];
}

// =========== MFMA F-precompute: F[ts][p][k] = sum_q wihP[bt][p][q]*convP[ts][k][q]
__global__ __launch_bounds__(256, 4) void k_fmat_mfma(
        const unsigned short* __restrict__ AH, const unsigned short* __restrict__ AL,
        const unsigned short* __restrict__ BH, const unsigned short* __restrict__ BL,
        unsigned short* __restrict__ FH, unsigned short* __restrict__ FL, int b) {
    const int ts = blockIdx.z;
    const int t = ts / NS;
    const int M0 = blockIdx.x * 96;
    const int N0 = blockIdx.y * 96;
    __shared__ __align__(16) char smem[24576];

    const int tid = threadIdx.x;
    const int lane = tid & 63;
    const int wave = tid >> 6;
    const int wm = wave & 1;
    const int wn = wave >> 1;
    const int l15 = lane & 15;
    const int kb = lane >> 4;
    const int ldso = (tid & 192) << 4;

    const unsigned short* gA[2];
    gA[0] = AH + (size_t)(b * 3 + t) * NPAD * CP;
    gA[1] = AL + (size_t)(b * 3 + t) * NPAD * CP;
    const unsigned short* gB[2];
    gB[0] = BH + (size_t)(b * 30 + ts) * 192 * 192;
    gB[1] = BL + (size_t)(b * 30 + ts) * 192 * 192;

    f32x4 acc[3][3];
    #pragma unroll
    for (int mi = 0; mi < 3; mi++)
        #pragma unroll
        for (int nj = 0; nj < 3; nj++) acc[mi][nj] = (f32x4){0.f, 0.f, 0.f, 0.f};

    for (int k = 0; k < 6; k++) {
        const int ko = k * 32;
        __syncthreads();
        #pragma unroll
        for (int i = 0; i < 6; i++) {
            int c = i * 256 + tid;
            int a = c / 384;
            int rem = c - a * 384;
            int r = rem >> 2, qs = rem & 3;
            int q = qs ^ ((r >> 1) & 3);
            const unsigned short* g = (a < 2) ? gA[a] : gB[a - 2];
            int row = ((a < 2) ? M0 : N0) + r;
            dma16(g + (size_t)row * CP + ko + q * 8, smem + i * 4096 + ldso);
        }
        __syncthreads();

        short8 ah[3], al[3], bh[3], bl[3];
        #pragma unroll
        for (int mi = 0; mi < 3; mi++) {
            int r = wm * 48 + mi * 16 + l15;
            int sl = (r * 4 + (kb ^ ((r >> 1) & 3))) * 16;
            ah[mi] = *(const short8*)(smem + sl);
            al[mi] = *(const short8*)(smem + 6144 + sl);
        }
        #pragma unroll
        for (int nj = 0; nj < 3; nj++) {
            int r = wn * 48 + nj * 16 + l15;
            int sl = (r * 4 + (kb ^ ((r >> 1) & 3))) * 16;
            bh[nj] = *(const short8*)(smem + 12288 + sl);
            bl[nj] = *(const short8*)(smem + 18432 + sl);
        }
        #pragma unroll
        for (int mi = 0; mi < 3; mi++)
            #pragma unroll
            for (int nj = 0; nj < 3; nj++) {
                acc[mi][nj] = __builtin_amdgcn_mfma_f32_16x16x32_bf16(
                    ah[mi], bh[nj], acc[mi][nj], 0, 0, 0);
                acc[mi][nj] = __builtin_amdgcn_mfma_f32_16x16x32_bf16(
                    al[mi], bh[nj], acc[mi][nj], 0, 0, 0);
                acc[mi][nj] = __builtin_amdgcn_mfma_f32_16x16x32_bf16(
                    ah[mi], bl[nj], acc[mi][nj], 0, 0, 0);
            }
    }
    #pragma unroll
    for (int mi = 0; mi < 3; mi++)
        #pragma unroll
        for (int nj = 0; nj < 3; nj++)
            #pragma unroll
            for (int r = 0; r < 4; r++) {
                int p = M0 + wm * 48 + mi * 16 + kb * 4 + r;
                int kc = N0 + wn * 48 + nj * 16 + l15;
                float val = acc[mi][nj][r];
                unsigned short hi = f2bf(val);
                size_t o = ((size_t)ts * NPAD + p) * CP + kc;
                FH[o] = hi;
                FL[o] = f2bf(val - bf2f(hi));
            }
}

// ------------------- h fp32 -> X0 hi/lo bf16 for the 3 type-chains
__global__ void k_split3(const float* __restrict__ h, unsigned short* __restrict__ XH,
                         unsigned short* __restrict__ XL) {
    int idx = blockIdx.x * 256 + threadIdx.x;
    if (idx >= NC) return;
    float f = h[idx];
    unsigned short hi = f2bf(f);
    unsigned short lo = f2bf(f - bf2f(hi));
    #pragma unroll
    for (int t = 0; t < NT; t++) {
        XH[(long)t * NC + idx] = hi;
        XL[(long)t * NC + idx] = lo;
    }
}

// ------------------- Agg hi/lo from X hi/lo via CSR gather
__global__ void k_agg(const unsigned short* __restrict__ XH, const unsigned short* __restrict__ XL,
                      unsigned short* __restrict__ AH, unsigned short* __restrict__ AL,
                      const int* __restrict__ off, const int* __restrict__ csrc) {
    int node = blockIdx.x;
    int t = blockIdx.y;
    int k = threadIdx.x;   // 192
    const unsigned short* Xh = XH + (long)t * NC;
    const unsigned short* Xl = XL + (long)t * NC;
    int e0 = off[t * N_NODES + node];
    int e1 = off[t * N_NODES + node + 1];
    float s = 0.f;
    for (int e = e0; e < e1; e++) {
        long base = (long)csrc[e] * CP + k;
        s += bf2f(Xh[base]) + bf2f(Xl[base]);
    }
    unsigned short hi = f2bf(s);
    long o = ((long)t * N_NODES + node) * CP + k;
    AH[o] = hi;
    AL[o] = f2bf(s - bf2f(hi));
}

// =================== hot kernel (R9 structure, M-tile 160): dual MFMA + reg GRU
// tile 160M x 96N, K=192 in 6 stages of 32; compensated bf16 (hh + lh + hl).
// ALL operands staged in LDS via global_load_lds DMA; XOR-swizzled 16B slots.
// 4000 = 25*160 exactly -> grid 25*6*3 = 450 <= 512 co-resident (single cohort,
// no ragged tail, no boundary clamps). LDS = 4*10240 (A) + 4*6144 (B) = 64 KB.
__global__ __launch_bounds__(256, 2) void k_step(
        const unsigned short* __restrict__ XcH, const unsigned short* __restrict__ XcL,
        const unsigned short* __restrict__ AgH, const unsigned short* __restrict__ AgL,
        const unsigned short* __restrict__ FH, const unsigned short* __restrict__ FL,
        const unsigned short* __restrict__ WH, const unsigned short* __restrict__ WL,
        const float* __restrict__ bih, const float* __restrict__ bhh,
        unsigned short* __restrict__ XnH, unsigned short* __restrict__ XnL,
        int b, int s) {
    const int t = blockIdx.z;
    const int ts = t * NS + s;
    const int M0 = blockIdx.x * 160;
    const int N0 = blockIdx.y * 96;

    // byte layout: A arrays (XH,GH,XL,GL) @ a*10240, 160 rows x 4 slots x 16B
    //              B arrays (FH,WH,FL,WL) @ 40960 + a*6144, 96 rows x 4 slots x 16B
    __shared__ __align__(16) char smem[65536];

    const int tid = threadIdx.x;
    const int lane = tid & 63;
    const int wave = tid >> 6;
    const int wm = wave & 1;      // M-half: 80 rows
    const int wn = wave >> 1;     // N-half: 48 rows
    const int l15 = lane & 15;
    const int kb = lane >> 4;

    const unsigned short* gA[4];
    gA[0] = XcH + (size_t)t * NC;
    gA[1] = AgH + (size_t)t * NC;
    gA[2] = XcL + (size_t)t * NC;
    gA[3] = AgL + (size_t)t * NC;
    const unsigned short* gB[4];
    gB[0] = FH + (size_t)ts * NPAD * CP;
    gB[1] = WH + (size_t)(b * 3 + t) * NPAD * CP;
    gB[2] = FL + (size_t)ts * NPAD * CP;
    gB[3] = WL + (size_t)(b * 3 + t) * NPAD * CP;

    f32x4 accGI[5][3], accGH[5][3];
    #pragma unroll
    for (int mi = 0; mi < 5; mi++)
        #pragma unroll
        for (int nj = 0; nj < 3; nj++) {
            accGI[mi][nj] = (f32x4){0.f, 0.f, 0.f, 0.f};
            accGH[mi][nj] = (f32x4){0.f, 0.f, 0.f, 0.f};
        }

    const int ldso = (tid & 192) << 4;

    for (int k = 0; k < 6; k++) {
        const int ko = k * 32;
        __syncthreads();
        // ---- A: 4 arrays x 160 rows x 4 slots = 2560 slots; 10 iters x 256
        #pragma unroll
        for (int i = 0; i < 10; i++) {
            int c = i * 256 + tid;
            int a = c / 640;
            int rem = c - a * 640;
            int r = rem >> 2, qs = rem & 3;
            int q = qs ^ ((r >> 1) & 3);
            dma16(gA[a] + (size_t)(M0 + r) * CP + ko + q * 8, smem + i * 4096 + ldso);
        }
        // ---- B: 4 arrays x 96 rows x 4 slots = 1536 slots; 6 iters x 256
        #pragma unroll
        for (int i = 0; i < 6; i++) {
            int c = i * 256 + tid;
            int a = c / 384;
            int rem = c - a * 384;
            int r = rem >> 2, qs = rem & 3;
            int q = qs ^ ((r >> 1) & 3);
            dma16(gB[a] + (size_t)(N0 + r) * CP + ko + q * 8, smem + 40960 + i * 4096 + ldso);
        }
        __syncthreads();

        short8 xh[5], gh[5], xl[5], gl[5];
        #pragma unroll
        for (int mi = 0; mi < 5; mi++) {
            int r = wm * 80 + mi * 16 + l15;
            int sl = (r * 4 + (kb ^ ((r >> 1) & 3))) * 16;
            xh[mi] = *(const short8*)(smem + sl);
            gh[mi] = *(const short8*)(smem + 10240 + sl);
            xl[mi] = *(const short8*)(smem + 20480 + sl);
            gl[mi] = *(const short8*)(smem + 30720 + sl);
        }
        short8 fh[3], wh[3], fl[3], wl[3];
        #pragma unroll
        for (int nj = 0; nj < 3; nj++) {
            int r = wn * 48 + nj * 16 + l15;
            int sl = (r * 4 + (kb ^ ((r >> 1) & 3))) * 16;
            fh[nj] = *(const short8*)(smem + 40960 + sl);
            wh[nj] = *(const short8*)(smem + 47104 + sl);
            fl[nj] = *(const short8*)(smem + 53248 + sl);
            wl[nj] = *(const short8*)(smem + 59392 + sl);
        }
        #pragma unroll
        for (int mi = 0; mi < 5; mi++)
            #pragma unroll
            for (int nj = 0; nj < 3; nj++) {
                accGI[mi][nj] = __builtin_amdgcn_mfma_f32_16x16x32_bf16(
                    gh[mi], fh[nj], accGI[mi][nj], 0, 0, 0);
                accGI[mi][nj] = __builtin_amdgcn_mfma_f32_16x16x32_bf16(
                    gl[mi], fh[nj], accGI[mi][nj], 0, 0, 0);
                accGI[mi][nj] = __builtin_amdgcn_mfma_f32_16x16x32_bf16(
                    gh[mi], fl[nj], accGI[mi][nj], 0, 0, 0);
                accGH[mi][nj] = __builtin_amdgcn_mfma_f32_16x16x32_bf16(
                    xh[mi], wh[nj], accGH[mi][nj], 0, 0, 0);
                accGH[mi][nj] = __builtin_amdgcn_mfma_f32_16x16x32_bf16(
                    xl[mi], wh[nj], accGH[mi][nj], 0, 0, 0);
                accGH[mi][nj] = __builtin_amdgcn_mfma_f32_16x16x32_bf16(
                    xh[mi], wl[nj], accGH[mi][nj], 0, 0, 0);
            }
    }

    // ---------------- register-only GRU epilogue
    const int J = blockIdx.y * 32 + wn * 16 + l15;
    const bool jv = (J < CC);
    const int Je = jv ? J : 0;
    const int bo = (b * 3 + t) * THREE_C;
    const float bir = bih[bo + Je], biz = bih[bo + CC + Je], bic = bih[bo + 2 * CC + Je];
    const float bhr = bhh[bo + Je], bhz = bhh[bo + CC + Je], bhc = bhh[bo + 2 * CC + Je];
    #pragma unroll
    for (int mi = 0; mi < 5; mi++) {
        #pragma unroll
        for (int r = 0; r < 4; r++) {
            int node = M0 + wm * 80 + mi * 16 + kb * 4 + r;
            if (jv) {
                size_t xi = (size_t)(t * N_NODES + node) * CP + J;
                float xold = bf2f(XcH[xi]) + bf2f(XcL[xi]);
                float rr = 1.f / (1.f + expf(-(accGI[mi][0][r] + bir + accGH[mi][0][r] + bhr)));
                float zz = 1.f / (1.f + expf(-(accGI[mi][1][r] + biz + accGH[mi][1][r] + bhz)));
                float cg = tanhf(accGI[mi][2][r] + bic + rr * (accGH[mi][2][r] + bhc));
                float outv = (1.f - zz) * cg + zz * xold;
                unsigned short oh = f2bf(outv);
                XnH[xi] = oh;
                XnL[xi] = f2bf(outv - bf2f(oh));
            }
        }
    }
}

// --------------------------------------------------------- LayerNorm + ReLU
__global__ void k_ln(float* __restrict__ h, const unsigned short* __restrict__ XH,
                     const unsigned short* __restrict__ XL,
                     const float* __restrict__ lnw, const float* __restrict__ lnb, int b) {
    int i = blockIdx.x;
    int c = threadIdx.x;
    long base = (long)i * CP + c;
    float v = 0.f;
    if (c < CC) {
        v = h[base];
        #pragma unroll
        for (int t = 0; t < NT; t++)
            v += bf2f(XH[(long)t * NC + base]) + bf2f(XL[(long)t * NC + base]);
    }
    float sv = v;
    for (int o = 32; o > 0; o >>= 1) sv += __shfl_down(sv, o);
    __shared__ float ls[3];
    __shared__ float bc[2];
    if ((threadIdx.x & 63) == 0) ls[threadIdx.x >> 6] = sv;
    __syncthreads();
    if (threadIdx.x == 0) bc[0] = (ls[0] + ls[1] + ls[2]) / (float)CC;
    __syncthreads();
    float mu = bc[0];
    float d = (c < CC) ? (v - mu) : 0.f;
    float s2 = d * d;
    for (int o = 32; o > 0; o >>= 1) s2 += __shfl_down(s2, o);
    __syncthreads();
    if ((threadIdx.x & 63) == 0) ls[threadIdx.x >> 6] = s2;
    __syncthreads();
    if (threadIdx.x == 0) bc[1] = (ls[0] + ls[1] + ls[2]) / (float)CC;
    __syncthreads();
    float var = bc[1];
    float y = 0.f;
    if (c < CC) {
        y = d * rsqrtf(var + 1e-5f) * lnw[b * CC + c] + lnb[b * CC + c];
        y = y > 0.f ? y : 0.f;
    }
    h[base] = y;
}

// --------------------------------------------------------------- pooling
__global__ void k_pool(const float* __restrict__ h, const int* __restrict__ batch,
                       float* __restrict__ hg, float* __restrict__ gcnt) {
    int idx = blockIdx.x * 256 + threadIdx.x;
    if (idx >= NC) return;
    int i = idx / CP, c = idx % CP;
    int g = batch[i];
    if (c < CC) atomicAdd(&hg[g * CP + c], h[idx]);
    if (c == 0) atomicAdd(&gcnt[g], 1.f);
}

__global__ void k_head1(const float* __restrict__ hg, const float* __restrict__ gcnt,
                        const float* __restrict__ w1, const float* __restrict__ b1,
                        float* __restrict__ z1) {
    int g = blockIdx.x;
    int jcol = threadIdx.x;
    if (jcol >= CC) return;
    float inv = 1.f / fmaxf(gcnt[g], 1.f);
    float acc = 0.f;
    for (int k = 0; k < CC; k++) acc += hg[g * CP + k] * inv * w1[k * CC + jcol];
    acc += b1[jcol];
    z1[g * CP + jcol] = fmaxf(acc, 0.f);
}

__global__ void k_head2(const float* __restrict__ z1, const float* __restrict__ w2,
                        const float* __restrict__ b2, float* __restrict__ out) {
    int idx = threadIdx.x;
    if (idx >= GG * 2) return;
    int g = idx / 2, o = idx % 2;
    float acc = 0.f;
    for (int k = 0; k < CC; k++) acc += z1[g * CP + k] * w2[k * 2 + o];
    out[g * 2 + o] = acc + b2[o];
}

// ================================================================ launch
extern "C" void kernel_launch(void* const* d_in, const int* in_sizes, int n_in,
                              void* d_out, int out_size, void* d_ws, size_t ws_size,
                              hipStream_t stream) {
    const float* xs   = (const float*)d_in[0];
    const float* conv = (const float*)d_in[1];
    const float* wih  = (const float*)d_in[2];
    const float* whh  = (const float*)d_in[3];
    const float* bih  = (const float*)d_in[4];
    const float* bhh  = (const float*)d_in[5];
    const float* lnw  = (const float*)d_in[6];
    const float* lnb  = (const float*)d_in[7];
    const float* hw1  = (const float*)d_in[8];
    const float* hb1  = (const float*)d_in[9];
    const float* hw2  = (const float*)d_in[10];
    const float* hb2  = (const float*)d_in[11];
    const int* xtype  = (const int*)d_in[12];
    const int* xtok   = (const int*)d_in[13];
    const int* ei     = (const int*)d_in[14];
    const int* et     = (const int*)d_in[15];
    const int* batch  = (const int*)d_in[16];
    float* out = (float*)d_out;

    char* ws = (char*)d_ws;
    size_t o = 0;
    auto alloc = [&](size_t nbytes) {
        size_t r = o;
        o = (o + nbytes + 255) & ~(size_t)255;
        return r;
    };
    float* h      = (float*)(ws + alloc((size_t)NC * 4));
    unsigned short* FH    = (unsigned short*)(ws + alloc((size_t)30 * NPAD * CP * 2));
    unsigned short* FL    = (unsigned short*)(ws + alloc((size_t)30 * NPAD * CP * 2));
    unsigned short* WHH   = (unsigned short*)(ws + alloc((size_t)15 * NPAD * CP * 2));
    unsigned short* WHL   = (unsigned short*)(ws + alloc((size_t)15 * NPAD * CP * 2));
    unsigned short* wihH  = (unsigned short*)(ws + alloc((size_t)15 * NPAD * CP * 2));
    unsigned short* wihL  = (unsigned short*)(ws + alloc((size_t)15 * NPAD * CP * 2));
    unsigned short* convH = (unsigned short*)(ws + alloc((size_t)150 * 192 * 192 * 2));
    unsigned short* convL = (unsigned short*)(ws + alloc((size_t)150 * 192 * 192 * 2));
    unsigned short* XAh = (unsigned short*)(ws + alloc((size_t)NT * NC * 2));
    unsigned short* XAl = (unsigned short*)(ws + alloc((size_t)NT * NC * 2));
    unsigned short* XBh = (unsigned short*)(ws + alloc((size_t)NT * NC * 2));
    unsigned short* XBl = (unsigned short*)(ws + alloc((size_t)NT * NC * 2));
    unsigned short* AggH = (unsigned short*)(ws + alloc((size_t)NT * NC * 2));
    unsigned short* AggL = (unsigned short*)(ws + alloc((size_t)NT * NC * 2));
    float* hg     = (float*)(ws + alloc((size_t)GG * CP * 4));
    float* gcnt   = (float*)(ws + alloc((size_t)GG * 4));
    float* z1buf  = (float*)(ws + alloc((size_t)GG * CP * 4));
    int* cnt      = (int*)(ws + alloc((size_t)NT * N_NODES * 4));
    int* offb     = (int*)(ws + alloc((size_t)(NT * N_NODES + 1) * 4));
    int* fillb    = (int*)(ws + alloc((size_t)NT * N_NODES * 4));
    int* csrc     = (int*)(ws + alloc((size_t)EE * 4));
    (void)ws_size; (void)n_in; (void)in_sizes; (void)out_size;

    hipMemsetAsync(cnt, 0, (size_t)NT * N_NODES * 4, stream);
    hipMemsetAsync(hg, 0, (size_t)GG * CP * 4, stream);
    hipMemsetAsync(gcnt, 0, (size_t)GG * 4, stream);

    k_build_h<<<(NC + 255) / 256, 256, 0, stream>>>(xs, xtype, xtok, h);
    k_split_gates<<<(int)((15L * NPAD * CP + 255) / 256), 256, 0, stream>>>(wih, wihH, wihL, 15);
    k_split_gates<<<(int)((15L * NPAD * CP + 255) / 256), 256, 0, stream>>>(whh, WHH, WHL, 15);
    k_split_conv<<<(int)((150L * 192 * 192 + 255) / 256), 256, 0, stream>>>(conv, convH, convL);
    k_edge_count<<<(EE + 255) / 256, 256, 0, stream>>>(ei, et, cnt);
    k_scan<<<1, 256, 0, stream>>>(cnt, offb, fillb);
    k_edge_fill<<<(EE + 255) / 256, 256, 0, stream>>>(ei, et, fillb, csrc);

    for (int b = 0; b < NB; b++) {
        k_fmat_mfma<<<dim3(6, 2, 30), 256, 0, stream>>>(wihH, wihL, convH, convL, FH, FL, b);
        k_split3<<<(NC + 255) / 256, 256, 0, stream>>>(h, XAh, XAl);
        unsigned short *curH = XAh, *curL = XAl, *nxtH = XBh, *nxtL = XBl;
        for (int s = 0; s < NS; s++) {
            k_agg<<<dim3(N_NODES, NT), CP, 0, stream>>>(curH, curL, AggH, AggL, offb, csrc);
            dim3 sg(25, 6, NT);   // 25 M-tiles (160 rows each, exact) x 6 N x types
            k_step<<<sg, 256, 0, stream>>>(curH, curL, AggH, AggL, FH, FL, WHH, WHL,
                                           bih, bhh, nxtH, nxtL, b, s);
            unsigned short* t1 = curH; curH = nxtH; nxtH = t1;
            unsigned short* t2 = curL; curL = nxtL; nxtL = t2;
        }
        k_ln<<<N_NODES, CP, 0, stream>>>(h, XAh, XAl, lnw, lnb, b);
    }

    k_pool<<<(NC + 255) / 256, 256, 0, stream>>>(h, batch, hg, gcnt);
    k_head1<<<GG, CP, 0, stream>>>(hg, gcnt, hw1, hb1, z1buf);
    k_head2<<<1, 64, 0, stream>>>(z1buf, hw2, hb2, out);
}

// Round 12
// 2549.423 us; speedup vs baseline: 1.5766x; 1.2950x over previous
//
#include <hip/hip_runtime.h>
#include <math.h>

#define N_NODES 4000
#define CC 191
#define CP 192
#define NT 3
#define NB 5
#define NS 10
#define EE 12000
#define GG 32
#define THREE_C 573
#define NC (N_NODES * CP)
#define NPAD 576

typedef __attribute__((ext_vector_type(8))) short short8;
typedef __attribute__((ext_vector_type(4))) float f32x4;

__device__ __forceinline__ unsigned short f2bf(float f) {
    unsigned u = __float_as_uint(f);
    unsigned r = (u + 0x7fffu + ((u >> 16) & 1u)) >> 16;
    return (unsigned short)r;
}
__device__ __forceinline__ float bf2f(unsigned short s) {
    return __uint_as_float(((unsigned)s) << 16);
}
// async global->LDS DMA, 16B per lane; lds dest = wave-uniform base + lane*16
__device__ __forceinline__ void dma16(const void* g, void* l) {
    __builtin_amdgcn_global_load_lds(
        (const __attribute__((address_space(1))) unsigned int*)g,
        (__attribute__((address_space(3))) unsigned int*)l, 16, 0, 0);
}

// ---------------------------------------------------------------- build h
__global__ void k_build_h(const float* __restrict__ xs, const int* __restrict__ xtype,
                          const int* __restrict__ xtok, float* __restrict__ h) {
    int idx = blockIdx.x * 256 + threadIdx.x;
    if (idx >= NC) return;
    int i = idx / CP, c = idx % CP;
    float v = 0.f;
    if (c < 60) {
        v = (xtype[i] == c) ? 1.f : 0.f;
    } else if (c < 189) {
        int tk = xtok[i];
        tk = tk < 0 ? 0 : (tk > 128 ? 128 : tk);
        v = (tk == c - 60) ? 1.f : 0.f;
    } else if (c < CC) {
        v = xs[i * 2 + (c - 189)];
    }
    h[idx] = v;
}

// ---- split gate-matrices (wih or whh, raw [nbt][573][191]) -> hi/lo bf16
// permuted rows: p -> B0=p/96, v=(p%96)>>4, u=p&15 : gate=v%3, j=B0*32+(v/3)*16+u
__global__ void k_split_gates(const float* __restrict__ src, unsigned short* __restrict__ H,
                              unsigned short* __restrict__ L, int nbt) {
    long tot = (long)nbt * NPAD * CP;
    long idx = (long)blockIdx.x * 256 + threadIdx.x;
    if (idx >= tot) return;
    int q = (int)(idx % CP);
    int p = (int)((idx / CP) % NPAD);
    int bt = (int)(idx / ((long)NPAD * CP));
    int B0 = p / 96, pr = p % 96;
    int v = pr >> 4, u = pr & 15;
    int g = v % 3;
    int j = B0 * 32 + (v / 3) * 16 + u;
    float val = 0.f;
    if (j < CC && q < CC) val = src[((long)bt * THREE_C + g * CC + j) * CC + q];
    unsigned short hi = f2bf(val);
    H[idx] = hi;
    L[idx] = f2bf(val - bf2f(hi));
}

// ---- split conv (raw [150][191][191]) -> hi/lo bf16 [150][192][192]
__global__ void k_split_conv(const float* __restrict__ src, unsigned short* __restrict__ H,
                             unsigned short* __restrict__ L) {
    long tot = 150L * 192 * 192;
    long idx = (long)blockIdx.x * 256 + threadIdx.x;
    if (idx >= tot) return;
    int q = (int)(idx % 192);
    int k = (int)((idx / 192) % 192);
    int ts = (int)(idx / (192 * 192));
    float val = 0.f;
    if (k < CC && q < CC) val = src[((long)ts * CC + k) * CC + q];
    unsigned short hi = f2bf(val);
    H[idx] = hi;
    L[idx] = f2bf(val - bf2f(hi));
}

// --------------------------------------------------------------- CSR build
__global__ void k_edge_count(const int* __restrict__ ei, const int* __restrict__ et,
                             int* __restrict__ cnt) {
    int e = blockIdx.x * 256 + threadIdx.x;
    if (e >= EE) return;
    atomicAdd(&cnt[et[e] * N_NODES + ei[EE + e]], 1);
}

__global__ void k_scan(const int* __restrict__ cnt, int* __restrict__ off, int* __restrict__ fill) {
    const int TOT = NT * N_NODES;
    const int CH = (TOT + 255) / 256;
    __shared__ int ls[256];
    int tid = threadIdx.x;
    int base = tid * CH;
    int s = 0;
    for (int u = 0; u < CH; u++) {
        int idx = base + u;
        if (idx < TOT) s += cnt[idx];
    }
    ls[tid] = s;
    __syncthreads();
    for (int d = 1; d < 256; d <<= 1) {
        int v = 0;
        if (tid >= d) v = ls[tid - d];
        __syncthreads();
        if (tid >= d) ls[tid] += v;
        __syncthreads();
    }
    int run = (tid > 0) ? ls[tid - 1] : 0;
    for (int u = 0; u < CH; u++) {
        int idx = base + u;
        if (idx < TOT) {
            off[idx] = run;
            fill[idx] = run;
            run += cnt[idx];
        }
    }
    if (tid == 255) off[TOT] = run;
}

__global__ void k_edge_fill(const int* __restrict__ ei, const int* __restrict__ et,
                            int* __restrict__ fill, int* __restrict__ csrc) {
    int e = blockIdx.x * 256 + threadIdx.x;
    if (e >= EE) return;
    int pos = atomicAdd(&fill[et[e] * N_NODES + ei[EE + e]], 1);
    csrc[pos] = ei[e];
}

// =========== MFMA F-precompute: F[ts][p][k] = sum_q wihP[bt][p][q]*convP[ts][k][q]
__global__ __launch_bounds__(256, 4) void k_fmat_mfma(
        const unsigned short* __restrict__ AH, const unsigned short* __restrict__ AL,
        const unsigned short* __restrict__ BH, const unsigned short* __restrict__ BL,
        unsigned short* __restrict__ FH, unsigned short* __restrict__ FL, int b) {
    const int ts = blockIdx.z;
    const int t = ts / NS;
    const int M0 = blockIdx.x * 96;
    const int N0 = blockIdx.y * 96;
    __shared__ __align__(16) char smem[24576];

    const int tid = threadIdx.x;
    const int lane = tid & 63;
    const int wave = tid >> 6;
    const int wm = wave & 1;
    const int wn = wave >> 1;
    const int l15 = lane & 15;
    const int kb = lane >> 4;
    const int ldso = (tid & 192) << 4;

    const unsigned short* gA[2];
    gA[0] = AH + (size_t)(b * 3 + t) * NPAD * CP;
    gA[1] = AL + (size_t)(b * 3 + t) * NPAD * CP;
    const unsigned short* gB[2];
    gB[0] = BH + (size_t)(b * 30 + ts) * 192 * 192;
    gB[1] = BL + (size_t)(b * 30 + ts) * 192 * 192;

    f32x4 acc[3][3];
    #pragma unroll
    for (int mi = 0; mi < 3; mi++)
        #pragma unroll
        for (int nj = 0; nj < 3; nj++) acc[mi][nj] = (f32x4){0.f, 0.f, 0.f, 0.f};

    for (int k = 0; k < 6; k++) {
        const int ko = k * 32;
        if (k) __syncthreads();
        #pragma unroll
        for (int i = 0; i < 6; i++) {
            int c = i * 256 + tid;
            int a = c / 384;
            int rem = c - a * 384;
            int r = rem >> 2, qs = rem & 3;
            int q = qs ^ ((r >> 1) & 3);
            const unsigned short* g = (a < 2) ? gA[a] : gB[a - 2];
            int row = ((a < 2) ? M0 : N0) + r;
            dma16(g + (size_t)row * CP + ko + q * 8, smem + i * 4096 + ldso);
        }
        __syncthreads();

        short8 ah[3], al[3], bh[3], bl[3];
        #pragma unroll
        for (int mi = 0; mi < 3; mi++) {
            int r = wm * 48 + mi * 16 + l15;
            int sl = (r * 4 + (kb ^ ((r >> 1) & 3))) * 16;
            ah[mi] = *(const short8*)(smem + sl);
            al[mi] = *(const short8*)(smem + 6144 + sl);
        }
        #pragma unroll
        for (int nj = 0; nj < 3; nj++) {
            int r = wn * 48 + nj * 16 + l15;
            int sl = (r * 4 + (kb ^ ((r >> 1) & 3))) * 16;
            bh[nj] = *(const short8*)(smem + 12288 + sl);
            bl[nj] = *(const short8*)(smem + 18432 + sl);
        }
        #pragma unroll
        for (int mi = 0; mi < 3; mi++)
            #pragma unroll
            for (int nj = 0; nj < 3; nj++) {
                acc[mi][nj] = __builtin_amdgcn_mfma_f32_16x16x32_bf16(
                    ah[mi], bh[nj], acc[mi][nj], 0, 0, 0);
                acc[mi][nj] = __builtin_amdgcn_mfma_f32_16x16x32_bf16(
                    al[mi], bh[nj], acc[mi][nj], 0, 0, 0);
                acc[mi][nj] = __builtin_amdgcn_mfma_f32_16x16x32_bf16(
                    ah[mi], bl[nj], acc[mi][nj], 0, 0, 0);
            }
    }
    #pragma unroll
    for (int mi = 0; mi < 3; mi++)
        #pragma unroll
        for (int nj = 0; nj < 3; nj++)
            #pragma unroll
            for (int r = 0; r < 4; r++) {
                int p = M0 + wm * 48 + mi * 16 + kb * 4 + r;
                int kc = N0 + wn * 48 + nj * 16 + l15;
                float val = acc[mi][nj][r];
                unsigned short hi = f2bf(val);
                size_t o = ((size_t)ts * NPAD + p) * CP + kc;
                FH[o] = hi;
                FL[o] = f2bf(val - bf2f(hi));
            }
}

// ------------------- h fp32 -> X0 hi/lo bf16 for the 3 type-chains
__global__ void k_split3(const float* __restrict__ h, unsigned short* __restrict__ XH,
                         unsigned short* __restrict__ XL) {
    int idx = blockIdx.x * 256 + threadIdx.x;
    if (idx >= NC) return;
    float f = h[idx];
    unsigned short hi = f2bf(f);
    unsigned short lo = f2bf(f - bf2f(hi));
    #pragma unroll
    for (int t = 0; t < NT; t++) {
        XH[(long)t * NC + idx] = hi;
        XL[(long)t * NC + idx] = lo;
    }
}

// ------------------- Agg hi/lo from X hi/lo via CSR gather
__global__ void k_agg(const unsigned short* __restrict__ XH, const unsigned short* __restrict__ XL,
                      unsigned short* __restrict__ AH, unsigned short* __restrict__ AL,
                      const int* __restrict__ off, const int* __restrict__ csrc) {
    int node = blockIdx.x;
    int t = blockIdx.y;
    int k = threadIdx.x;   // 192
    const unsigned short* Xh = XH + (long)t * NC;
    const unsigned short* Xl = XL + (long)t * NC;
    int e0 = off[t * N_NODES + node];
    int e1 = off[t * N_NODES + node + 1];
    float s = 0.f;
    for (int e = e0; e < e1; e++) {
        long base = (long)csrc[e] * CP + k;
        s += bf2f(Xh[base]) + bf2f(Xl[base]);
    }
    unsigned short hi = f2bf(s);
    long o = ((long)t * N_NODES + node) * CP + k;
    AH[o] = hi;
    AL[o] = f2bf(s - bf2f(hi));
}

// =================== hot kernel (R9-proven): dual MFMA GEMM + register GRU
// tile 128M x 96N, K=192 in 6 stages of 32; compensated bf16 (hh + lh + hl).
// ALL operands staged in LDS via global_load_lds DMA; XOR-swizzled 16B slots.
// grid-x = 32 (== 0 mod 8): all 6 N-blocks sharing an A-tile land on ONE XCD,
// so its L2 serves the A re-reads (R11 showed x=25 breaks this: FETCH 5x).
// Changes vs R9: skip the redundant k==0 top barrier; hoist epilogue xold loads
// above the K-loop (loop-invariant addresses; barriers blocked compiler motion).
__global__ __launch_bounds__(256, 2) void k_step(
        const unsigned short* __restrict__ XcH, const unsigned short* __restrict__ XcL,
        const unsigned short* __restrict__ AgH, const unsigned short* __restrict__ AgL,
        const unsigned short* __restrict__ FH, const unsigned short* __restrict__ FL,
        const unsigned short* __restrict__ WH, const unsigned short* __restrict__ WL,
        const float* __restrict__ bih, const float* __restrict__ bhh,
        unsigned short* __restrict__ XnH, unsigned short* __restrict__ XnL,
        int b, int s) {
    const int t = blockIdx.z;
    const int ts = t * NS + s;
    const int M0 = blockIdx.x * 128;
    const int N0 = blockIdx.y * 96;

    // byte layout: A arrays (XH,GH,XL,GL) @ a*8192, 128 rows x 4 slots x 16B
    //              B arrays (FH,WH,FL,WL) @ 32768 + a*6144, 96 rows x 4 slots x 16B
    __shared__ __align__(16) char smem[57344];

    const int tid = threadIdx.x;
    const int lane = tid & 63;
    const int wave = tid >> 6;
    const int wm = wave & 1;
    const int wn = wave >> 1;
    const int l15 = lane & 15;
    const int kb = lane >> 4;

    const unsigned short* gA[4];
    gA[0] = XcH + (size_t)t * NC;
    gA[1] = AgH + (size_t)t * NC;
    gA[2] = XcL + (size_t)t * NC;
    gA[3] = AgL + (size_t)t * NC;
    const unsigned short* gB[4];
    gB[0] = FH + (size_t)ts * NPAD * CP;
    gB[1] = WH + (size_t)(b * 3 + t) * NPAD * CP;
    gB[2] = FL + (size_t)ts * NPAD * CP;
    gB[3] = WL + (size_t)(b * 3 + t) * NPAD * CP;

    // ---- hoisted epilogue state: xold for this lane's (node, J) pairs
    const int J = blockIdx.y * 32 + wn * 16 + l15;
    const bool jv = (J < CC);
    const int Je = jv ? J : 0;
    float xold[4][4];
    #pragma unroll
    for (int mi = 0; mi < 4; mi++)
        #pragma unroll
        for (int r = 0; r < 4; r++) {
            int node = M0 + wm * 64 + mi * 16 + kb * 4 + r;
            if (node >= N_NODES) node = N_NODES - 1;
            size_t xi = (size_t)(t * N_NODES + node) * CP + Je;
            xold[mi][r] = bf2f(gA[0][xi - (size_t)t * NC + (size_t)t * NC]) + bf2f(XcL[xi]);
        }

    f32x4 accGI[4][3], accGH[4][3];
    #pragma unroll
    for (int mi = 0; mi < 4; mi++)
        #pragma unroll
        for (int nj = 0; nj < 3; nj++) {
            accGI[mi][nj] = (f32x4){0.f, 0.f, 0.f, 0.f};
            accGH[mi][nj] = (f32x4){0.f, 0.f, 0.f, 0.f};
        }

    const int ldso = (tid & 192) << 4;
    const int qsA = tid & 3;
    const int rA_lo = tid >> 2;

    for (int k = 0; k < 6; k++) {
        const int ko = k * 32;
        if (k) __syncthreads();   // k==0: LDS not yet live, barrier unnecessary
        // ---- A: 4 arrays x 128 rows x 32 half; iter i covers 256 slots
        #pragma unroll
        for (int i = 0; i < 8; i++) {
            int a = i >> 1;
            int r = (i & 1) * 64 + rA_lo;
            int q = qsA ^ ((r >> 1) & 3);
            int node = M0 + r; node = node < N_NODES ? node : N_NODES - 1;
            dma16(gA[a] + (size_t)node * CP + ko + q * 8, smem + i * 4096 + ldso);
        }
        // ---- B: 4 arrays x 96 rows x 32 half
        #pragma unroll
        for (int i = 0; i < 6; i++) {
            int c = i * 256 + tid;
            int a = c / 384;
            int rem = c - a * 384;
            int r = rem >> 2, qs = rem & 3;
            int q = qs ^ ((r >> 1) & 3);
            dma16(gB[a] + (size_t)(N0 + r) * CP + ko + q * 8, smem + 32768 + i * 4096 + ldso);
        }
        __syncthreads();

        short8 xh[4], gh[4], xl[4], gl[4];
        #pragma unroll
        for (int mi = 0; mi < 4; mi++) {
            int r = wm * 64 + mi * 16 + l15;
            int sl = (r * 4 + (kb ^ ((r >> 1) & 3))) * 16;
            xh[mi] = *(const short8*)(smem + sl);
            gh[mi] = *(const short8*)(smem + 8192 + sl);
            xl[mi] = *(const short8*)(smem + 16384 + sl);
            gl[mi] = *(const short8*)(smem + 24576 + sl);
        }
        short8 fh[3], wh[3], fl[3], wl[3];
        #pragma unroll
        for (int nj = 0; nj < 3; nj++) {
            int r = wn * 48 + nj * 16 + l15;
            int sl = (r * 4 + (kb ^ ((r >> 1) & 3))) * 16;
            fh[nj] = *(const short8*)(smem + 32768 + sl);
            wh[nj] = *(const short8*)(smem + 38912 + sl);
            fl[nj] = *(const short8*)(smem + 45056 + sl);
            wl[nj] = *(const short8*)(smem + 51200 + sl);
        }
        #pragma unroll
        for (int mi = 0; mi < 4; mi++)
            #pragma unroll
            for (int nj = 0; nj < 3; nj++) {
                accGI[mi][nj] = __builtin_amdgcn_mfma_f32_16x16x32_bf16(
                    gh[mi], fh[nj], accGI[mi][nj], 0, 0, 0);
                accGI[mi][nj] = __builtin_amdgcn_mfma_f32_16x16x32_bf16(
                    gl[mi], fh[nj], accGI[mi][nj], 0, 0, 0);
                accGI[mi][nj] = __builtin_amdgcn_mfma_f32_16x16x32_bf16(
                    gh[mi], fl[nj], accGI[mi][nj], 0, 0, 0);
                accGH[mi][nj] = __builtin_amdgcn_mfma_f32_16x16x32_bf16(
                    xh[mi], wh[nj], accGH[mi][nj], 0, 0, 0);
                accGH[mi][nj] = __builtin_amdgcn_mfma_f32_16x16x32_bf16(
                    xl[mi], wh[nj], accGH[mi][nj], 0, 0, 0);
                accGH[mi][nj] = __builtin_amdgcn_mfma_f32_16x16x32_bf16(
                    xh[mi], wl[nj], accGH[mi][nj], 0, 0, 0);
            }
    }

    // ---------------- register-only GRU epilogue
    const int bo = (b * 3 + t) * THREE_C;
    const float bir = bih[bo + Je], biz = bih[bo + CC + Je], bic = bih[bo + 2 * CC + Je];
    const float bhr = bhh[bo + Je], bhz = bhh[bo + CC + Je], bhc = bhh[bo + 2 * CC + Je];
    #pragma unroll
    for (int mi = 0; mi < 4; mi++) {
        #pragma unroll
        for (int r = 0; r < 4; r++) {
            int node = M0 + wm * 64 + mi * 16 + kb * 4 + r;
            if (node < N_NODES && jv) {
                size_t xi = (size_t)(t * N_NODES + node) * CP + J;
                float rr = 1.f / (1.f + expf(-(accGI[mi][0][r] + bir + accGH[mi][0][r] + bhr)));
                float zz = 1.f / (1.f + expf(-(accGI[mi][1][r] + biz + accGH[mi][1][r] + bhz)));
                float cg = tanhf(accGI[mi][2][r] + bic + rr * (accGH[mi][2][r] + bhc));
                float outv = (1.f - zz) * cg + zz * xold[mi][r];
                unsigned short oh = f2bf(outv);
                XnH[xi] = oh;
                XnL[xi] = f2bf(outv - bf2f(oh));
            }
        }
    }
}

// --------------------------------------------------------- LayerNorm + ReLU
__global__ void k_ln(float* __restrict__ h, const unsigned short* __restrict__ XH,
                     const unsigned short* __restrict__ XL,
                     const float* __restrict__ lnw, const float* __restrict__ lnb, int b) {
    int i = blockIdx.x;
    int c = threadIdx.x;
    long base = (long)i * CP + c;
    float v = 0.f;
    if (c < CC) {
        v = h[base];
        #pragma unroll
        for (int t = 0; t < NT; t++)
            v += bf2f(XH[(long)t * NC + base]) + bf2f(XL[(long)t * NC + base]);
    }
    float sv = v;
    for (int o = 32; o > 0; o >>= 1) sv += __shfl_down(sv, o);
    __shared__ float ls[3];
    __shared__ float bc[2];
    if ((threadIdx.x & 63) == 0) ls[threadIdx.x >> 6] = sv;
    __syncthreads();
    if (threadIdx.x == 0) bc[0] = (ls[0] + ls[1] + ls[2]) / (float)CC;
    __syncthreads();
    float mu = bc[0];
    float d = (c < CC) ? (v - mu) : 0.f;
    float s2 = d * d;
    for (int o = 32; o > 0; o >>= 1) s2 += __shfl_down(s2, o);
    __syncthreads();
    if ((threadIdx.x & 63) == 0) ls[threadIdx.x >> 6] = s2;
    __syncthreads();
    if (threadIdx.x == 0) bc[1] = (ls[0] + ls[1] + ls[2]) / (float)CC;
    __syncthreads();
    float var = bc[1];
    float y = 0.f;
    if (c < CC) {
        y = d * rsqrtf(var + 1e-5f) * lnw[b * CC + c] + lnb[b * CC + c];
        y = y > 0.f ? y : 0.f;
    }
    h[base] = y;
}

// --------------------------------------------------------------- pooling
__global__ void k_pool(const float* __restrict__ h, const int* __restrict__ batch,
                       float* __restrict__ hg, float* __restrict__ gcnt) {
    int idx = blockIdx.x * 256 + threadIdx.x;
    if (idx >= NC) return;
    int i = idx / CP, c = idx % CP;
    int g = batch[i];
    if (c < CC) atomicAdd(&hg[g * CP + c], h[idx]);
    if (c == 0) atomicAdd(&gcnt[g], 1.f);
}

__global__ void k_head1(const float* __restrict__ hg, const float* __restrict__ gcnt,
                        const float* __restrict__ w1, const float* __restrict__ b1,
                        float* __restrict__ z1) {
    int g = blockIdx.x;
    int jcol = threadIdx.x;
    if (jcol >= CC) return;
    float inv = 1.f / fmaxf(gcnt[g], 1.f);
    float acc = 0.f;
    for (int k = 0; k < CC; k++) acc += hg[g * CP + k] * inv * w1[k * CC + jcol];
    acc += b1[jcol];
    z1[g * CP + jcol] = fmaxf(acc, 0.f);
}

__global__ void k_head2(const float* __restrict__ z1, const float* __restrict__ w2,
                        const float* __restrict__ b2, float* __restrict__ out) {
    int idx = threadIdx.x;
    if (idx >= GG * 2) return;
    int g = idx / 2, o = idx % 2;
    float acc = 0.f;
    for (int k = 0; k < CC; k++) acc += z1[g * CP + k] * w2[k * 2 + o];
    out[g * 2 + o] = acc + b2[o];
}

// ================================================================ launch
extern "C" void kernel_launch(void* const* d_in, const int* in_sizes, int n_in,
                              void* d_out, int out_size, void* d_ws, size_t ws_size,
                              hipStream_t stream) {
    const float* xs   = (const float*)d_in[0];
    const float* conv = (const float*)d_in[1];
    const float* wih  = (const float*)d_in[2];
    const float* whh  = (const float*)d_in[3];
    const float* bih  = (const float*)d_in[4];
    const float* bhh  = (const float*)d_in[5];
    const float* lnw  = (const float*)d_in[6];
    const float* lnb  = (const float*)d_in[7];
    const float* hw1  = (const float*)d_in[8];
    const float* hb1  = (const float*)d_in[9];
    const float* hw2  = (const float*)d_in[10];
    const float* hb2  = (const float*)d_in[11];
    const int* xtype  = (const int*)d_in[12];
    const int* xtok   = (const int*)d_in[13];
    const int* ei     = (const int*)d_in[14];
    const int* et     = (const int*)d_in[15];
    const int* batch  = (const int*)d_in[16];
    float* out = (float*)d_out;

    char* ws = (char*)d_ws;
    size_t o = 0;
    auto alloc = [&](size_t nbytes) {
        size_t r = o;
        o = (o + nbytes + 255) & ~(size_t)255;
        return r;
    };
    float* h      = (float*)(ws + alloc((size_t)NC * 4));
    unsigned short* FH    = (unsigned short*)(ws + alloc((size_t)30 * NPAD * CP * 2));
    unsigned short* FL    = (unsigned short*)(ws + alloc((size_t)30 * NPAD * CP * 2));
    unsigned short* WHH   = (unsigned short*)(ws + alloc((size_t)15 * NPAD * CP * 2));
    unsigned short* WHL   = (unsigned short*)(ws + alloc((size_t)15 * NPAD * CP * 2));
    unsigned short* wihH  = (unsigned short*)(ws + alloc((size_t)15 * NPAD * CP * 2));
    unsigned short* wihL  = (unsigned short*)(ws + alloc((size_t)15 * NPAD * CP * 2));
    unsigned short* convH = (unsigned short*)(ws + alloc((size_t)150 * 192 * 192 * 2));
    unsigned short* convL = (unsigned short*)(ws + alloc((size_t)150 * 192 * 192 * 2));
    unsigned short* XAh = (unsigned short*)(ws + alloc((size_t)NT * NC * 2));
    unsigned short* XAl = (unsigned short*)(ws + alloc((size_t)NT * NC * 2));
    unsigned short* XBh = (unsigned short*)(ws + alloc((size_t)NT * NC * 2));
    unsigned short* XBl = (unsigned short*)(ws + alloc((size_t)NT * NC * 2));
    unsigned short* AggH = (unsigned short*)(ws + alloc((size_t)NT * NC * 2));
    unsigned short* AggL = (unsigned short*)(ws + alloc((size_t)NT * NC * 2));
    float* hg     = (float*)(ws + alloc((size_t)GG * CP * 4));
    float* gcnt   = (float*)(ws + alloc((size_t)GG * 4));
    float* z1buf  = (float*)(ws + alloc((size_t)GG * CP * 4));
    int* cnt      = (int*)(ws + alloc((size_t)NT * N_NODES * 4));
    int* offb     = (int*)(ws + alloc((size_t)(NT * N_NODES + 1) * 4));
    int* fillb    = (int*)(ws + alloc((size_t)NT * N_NODES * 4));
    int* csrc     = (int*)(ws + alloc((size_t)EE * 4));
    (void)ws_size; (void)n_in; (void)in_sizes; (void)out_size;

    hipMemsetAsync(cnt, 0, (size_t)NT * N_NODES * 4, stream);
    hipMemsetAsync(hg, 0, (size_t)GG * CP * 4, stream);
    hipMemsetAsync(gcnt, 0, (size_t)GG * 4, stream);

    k_build_h<<<(NC + 255) / 256, 256, 0, stream>>>(xs, xtype, xtok, h);
    k_split_gates<<<(int)((15L * NPAD * CP + 255) / 256), 256, 0, stream>>>(wih, wihH, wihL, 15);
    k_split_gates<<<(int)((15L * NPAD * CP + 255) / 256), 256, 0, stream>>>(whh, WHH, WHL, 15);
    k_split_conv<<<(int)((150L * 192 * 192 + 255) / 256), 256, 0, stream>>>(conv, convH, convL);
    k_edge_count<<<(EE + 255) / 256, 256, 0, stream>>>(ei, et, cnt);
    k_scan<<<1, 256, 0, stream>>>(cnt, offb, fillb);
    k_edge_fill<<<(EE + 255) / 256, 256, 0, stream>>>(ei, et, fillb, csrc);

    for (int b = 0; b < NB; b++) {
        k_fmat_mfma<<<dim3(6, 2, 30), 256, 0, stream>>>(wihH, wihL, convH, convL, FH, FL, b);
        k_split3<<<(NC + 255) / 256, 256, 0, stream>>>(h, XAh, XAl);
        unsigned short *curH = XAh, *curL = XAl, *nxtH = XBh, *nxtL = XBl;
        for (int s = 0; s < NS; s++) {
            k_agg<<<dim3(N_NODES, NT), CP, 0, stream>>>(curH, curL, AggH, AggL, offb, csrc);
            dim3 sg(32, 6, NT);   // grid-x 32 == 0 mod 8: A-sharing blocks on one XCD
            k_step<<<sg, 256, 0, stream>>>(curH, curL, AggH, AggL, FH, FL, WHH, WHL,
                                           bih, bhh, nxtH, nxtL, b, s);
            unsigned short* t1 = curH; curH = nxtH; nxtH = t1;
            unsigned short* t2 = curL; curL = nxtL; nxtL = t2;
        }
        k_ln<<<N_NODES, CP, 0, stream>>>(h, XAh, XAl, lnw, lnb, b);
    }

    k_pool<<<(NC + 255) / 256, 256, 0, stream>>>(h, batch, hg, gcnt);
    k_head1<<<GG, CP, 0, stream>>>(hg, gcnt, hw1, hb1, z1buf);
    k_head2<<<1, 64, 0, stream>>>(z1buf, hw2, hb2, out);
}